// Round 1
// baseline (110.022 us; speedup 1.0000x reference)
//
#include <hip/hip_runtime.h>

#define VOCAB 100000
#define HIDDEN 128
#define BATCH 1024
#define LEN 200

// ---------------------------------------------------------------------------
// Kernel 1: transpose W [HIDDEN][VOCAB] -> WT [VOCAB][HIDDEN]
// Tile: 32 h x 128 v, block 256 threads, LDS [32][133] (133 coprime w/ 32
// banks in the strided-read direction -> conflict-free store phase).
// Grid: (ceil(VOCAB/128)=782, HIDDEN/32=4). Guards handle the partial tail.
// ---------------------------------------------------------------------------
__global__ __launch_bounds__(256) void wt_transpose_kernel(
    const float* __restrict__ W, float* __restrict__ WT) {
    __shared__ float tile[32][133];
    const int v0 = blockIdx.x * 128;
    const int h0 = blockIdx.y * 32;
    const int tid = threadIdx.x;

    // Load phase: coalesced float4 along v. 32 h-rows x 32 float4-cols.
    const int vx = tid & 31;   // float4 column within tile
    const int hy = tid >> 5;   // 8 h-rows per pass
#pragma unroll
    for (int i = 0; i < 4; ++i) {
        const int h = hy + i * 8;              // 0..31 local h
        const int gv = v0 + vx * 4;
        if (gv + 3 < VOCAB) {
            const float4 f = *reinterpret_cast<const float4*>(
                &W[(size_t)(h0 + h) * VOCAB + gv]);
            tile[h][vx * 4 + 0] = f.x;
            tile[h][vx * 4 + 1] = f.y;
            tile[h][vx * 4 + 2] = f.z;
            tile[h][vx * 4 + 3] = f.w;
        } else {
#pragma unroll
            for (int k = 0; k < 4; ++k)
                if (gv + k < VOCAB)
                    tile[h][vx * 4 + k] = W[(size_t)(h0 + h) * VOCAB + gv + k];
        }
    }
    __syncthreads();

    // Store phase: coalesced along h (32 lanes x 4B = 128B per store).
    const int hx = tid & 31;   // local h (lane dimension)
    const int vy = tid >> 5;   // 8 v-rows per pass, 16 passes
#pragma unroll
    for (int i = 0; i < 16; ++i) {
        const int v = vy + i * 8;              // 0..127 local v
        const int gv = v0 + v;
        if (gv < VOCAB)
            WT[(size_t)gv * HIDDEN + h0 + hx] = tile[hx][v];
    }
}

// ---------------------------------------------------------------------------
// Kernel 2: gather-sum.  One block per batch row, 512 threads (8 waves).
// tid&31 = hq (float4 quad of hidden dim), tid>>5 = chunk (16 L-chunks).
// Each chunk accumulates LEN/16 embeddings; LDS tree-reduce; fused bias.
// Every gather is a 32-lane x 16B = 512B fully-coalesced contiguous read.
// ---------------------------------------------------------------------------
__global__ __launch_bounds__(512) void bag_gather_kernel(
    const int* __restrict__ ids, const float* __restrict__ WT,
    const float* __restrict__ bias, float* __restrict__ out) {
    __shared__ int sid[LEN];
    __shared__ float4 part[16][32];

    const int b = blockIdx.x;
    const int tid = threadIdx.x;

    for (int l = tid; l < LEN; l += 512) sid[l] = ids[b * LEN + l];
    __syncthreads();

    const int hq = tid & 31;
    const int chunk = tid >> 5;
    const float4* __restrict__ WT4 = reinterpret_cast<const float4*>(WT);

    float4 acc = make_float4(0.f, 0.f, 0.f, 0.f);
    for (int l = chunk; l < LEN; l += 16) {
        const int id = sid[l];
        const float4 w = WT4[(size_t)id * (HIDDEN / 4) + hq];
        acc.x += w.x; acc.y += w.y; acc.z += w.z; acc.w += w.w;
    }
    part[chunk][hq] = acc;
    __syncthreads();

#pragma unroll
    for (int s = 8; s > 0; s >>= 1) {
        if (chunk < s) {
            const float4 o = part[chunk + s][hq];
            float4 m = part[chunk][hq];
            m.x += o.x; m.y += o.y; m.z += o.z; m.w += o.w;
            part[chunk][hq] = m;
        }
        __syncthreads();
    }

    if (chunk == 0) {
        float4 r = part[0][hq];
        const float4 bb = reinterpret_cast<const float4*>(bias)[hq];
        r.x += bb.x; r.y += bb.y; r.z += bb.z; r.w += bb.w;
        reinterpret_cast<float4*>(out)[(size_t)b * (HIDDEN / 4) + hq] = r;
    }
}

// ---------------------------------------------------------------------------
// Fallback (ws too small): direct strided gather from original W layout.
// Correct but slow; only used if the harness workspace can't hold WT.
// ---------------------------------------------------------------------------
__global__ __launch_bounds__(HIDDEN) void bag_direct_kernel(
    const int* __restrict__ ids, const float* __restrict__ W,
    const float* __restrict__ bias, float* __restrict__ out) {
    __shared__ int sid[LEN];
    const int b = blockIdx.x;
    const int h = threadIdx.x;
    for (int l = h; l < LEN; l += HIDDEN) sid[l] = ids[b * LEN + l];
    __syncthreads();
    float acc = 0.f;
    for (int l = 0; l < LEN; ++l)
        acc += W[(size_t)h * VOCAB + sid[l]];
    out[(size_t)b * HIDDEN + h] = acc + bias[h];
}

extern "C" void kernel_launch(void* const* d_in, const int* in_sizes, int n_in,
                              void* d_out, int out_size, void* d_ws, size_t ws_size,
                              hipStream_t stream) {
    const int*   ids  = (const int*)d_in[0];
    const float* W    = (const float*)d_in[1];
    const float* bias = (const float*)d_in[2];
    float*       out  = (float*)d_out;

    const size_t need = (size_t)VOCAB * HIDDEN * sizeof(float);
    if (ws_size >= need) {
        float* WT = (float*)d_ws;
        wt_transpose_kernel<<<dim3((VOCAB + 127) / 128, HIDDEN / 32), 256, 0, stream>>>(W, WT);
        bag_gather_kernel<<<BATCH, 512, 0, stream>>>(ids, WT, bias, out);
    } else {
        bag_direct_kernel<<<BATCH, HIDDEN, 0, stream>>>(ids, W, bias, out);
    }
}

// Round 4
// 108.886 us; speedup vs baseline: 1.0104x; 1.0104x over previous
//
#include <hip/hip_runtime.h>
#include <hip/hip_fp16.h>

#define VOCAB 100000
#define HIDDEN 128
#define BATCH 1024
#define LEN 200
#define TP_V 64   // vocab-tile of the transpose kernel

typedef float f32x4 __attribute__((ext_vector_type(4)));

// ---------------------------------------------------------------------------
// Kernel 1: transpose + downconvert  W f32 [HIDDEN][VOCAB] -> WT fp16 [VOCAB][HIDDEN]
// Block 256 threads, tile = 64 v x 128 h (full hidden dim).
// LDS tile stored TRANSPOSED [v][h] with stride 133.
// Load: nontemporal float4 (W is single-use — don't pollute L2/L3).
// Store: thread packs 8 fp16 -> one 16B store; a wave writes 4 consecutive
// WT rows = 1024 B fully contiguous.
// ---------------------------------------------------------------------------
__global__ __launch_bounds__(256) void wt_transpose_f16(
    const float* __restrict__ W, __half* __restrict__ WT) {
    __shared__ float tile[TP_V][133];          // [v][h]
    const int v0 = blockIdx.x * TP_V;
    const int t  = threadIdx.x;

    const int vx = t & 15;    // float4 column (16 x 4 = 64 v)
    const int hy = t >> 4;    // h-row; 16 h per pass, 8 passes
#pragma unroll
    for (int p = 0; p < 8; ++p) {
        const int h  = hy + p * 16;
        const int gv = v0 + vx * 4;
        f32x4 f;
        if (gv + 3 < VOCAB) {
            f = __builtin_nontemporal_load(
                reinterpret_cast<const f32x4*>(&W[(size_t)h * VOCAB + gv]));
        } else {
            f[0] = (gv + 0 < VOCAB) ? W[(size_t)h * VOCAB + gv + 0] : 0.f;
            f[1] = (gv + 1 < VOCAB) ? W[(size_t)h * VOCAB + gv + 1] : 0.f;
            f[2] = (gv + 2 < VOCAB) ? W[(size_t)h * VOCAB + gv + 2] : 0.f;
            f[3] = (gv + 3 < VOCAB) ? W[(size_t)h * VOCAB + gv + 3] : 0.f;
        }
        tile[vx * 4 + 0][h] = f[0];
        tile[vx * 4 + 1][h] = f[1];
        tile[vx * 4 + 2][h] = f[2];
        tile[vx * 4 + 3][h] = f[3];
    }
    __syncthreads();

    const int h8 = (t & 15) * 8;
#pragma unroll
    for (int p = 0; p < 4; ++p) {
        const int v  = (t >> 4) + p * 16;
        const int gv = v0 + v;
        if (gv < VOCAB) {
            __half hb[8];
#pragma unroll
            for (int k = 0; k < 8; ++k) hb[k] = __float2half_rn(tile[v][h8 + k]);
            *reinterpret_cast<float4*>(&WT[(size_t)gv * HIDDEN + h8]) =
                *reinterpret_cast<const float4*>(hb);
        }
    }
}

// ---------------------------------------------------------------------------
// Kernel 2: gather-sum from fp16 WT.  One block per batch row, 512 threads.
// t&15 = 16B-slot within the 256 B row (g), t>>4 = L-chunk (32 chunks).
// A wave's 64 lanes span 16 g-slots x 4 chunks -> each wave instruction reads
// 4 consecutive 256 B rows, 16 B/lane fully coalesced.
// Reduce: 2 shfl_xor butterfly steps fold the 4 in-wave chunks (lane bits
// 4,5), then part[8][128] in LDS + single barrier + 8-way sum, fused bias.
// ---------------------------------------------------------------------------
__global__ __launch_bounds__(512) void bag_gather_f16(
    const int* __restrict__ ids, const __half* __restrict__ WT,
    const float* __restrict__ bias, float* __restrict__ out) {
    __shared__ int   sid[LEN];
    __shared__ float part[8][HIDDEN];   // 4 KB

    const int b = blockIdx.x;
    const int t = threadIdx.x;

    for (int l = t; l < LEN; l += 512) sid[l] = ids[b * LEN + l];
    __syncthreads();

    const int g     = t & 15;    // 8-h group within row
    const int chunk = t >> 4;    // 0..31

    float acc[8];
#pragma unroll
    for (int k = 0; k < 8; ++k) acc[k] = 0.f;

    for (int l = chunk; l < LEN; l += 32) {
        const int id = sid[l];
        const float4 q = *reinterpret_cast<const float4*>(
            WT + (size_t)id * HIDDEN + g * 8);
        const __half2* h2 = reinterpret_cast<const __half2*>(&q);
#pragma unroll
        for (int k = 0; k < 4; ++k) {
            const float2 f = __half22float2(h2[k]);
            acc[2 * k + 0] += f.x;
            acc[2 * k + 1] += f.y;
        }
    }

    // In-wave fold over chunk bits (lane bits 4 and 5).
#pragma unroll
    for (int k = 0; k < 8; ++k) {
        acc[k] += __shfl_xor(acc[k], 16);
        acc[k] += __shfl_xor(acc[k], 32);
    }
    const int wave = t >> 6;          // 0..7
    if ((t & 63) < 16) {
#pragma unroll
        for (int k = 0; k < 8; ++k) part[wave][g * 8 + k] = acc[k];
    }
    __syncthreads();

    if (t < HIDDEN) {
        float s = 0.f;
#pragma unroll
        for (int w = 0; w < 8; ++w) s += part[w][t];
        out[(size_t)b * HIDDEN + t] = s + bias[t];
    }
}

// ---------------------------------------------------------------------------
// Fallback (ws too small): direct strided gather from original W layout.
// ---------------------------------------------------------------------------
__global__ __launch_bounds__(HIDDEN) void bag_direct_kernel(
    const int* __restrict__ ids, const float* __restrict__ W,
    const float* __restrict__ bias, float* __restrict__ out) {
    __shared__ int sid[LEN];
    const int b = blockIdx.x;
    const int h = threadIdx.x;
    for (int l = h; l < LEN; l += HIDDEN) sid[l] = ids[b * LEN + l];
    __syncthreads();
    float acc = 0.f;
    for (int l = 0; l < LEN; ++l)
        acc += W[(size_t)h * VOCAB + sid[l]];
    out[(size_t)b * HIDDEN + h] = acc + bias[h];
}

extern "C" void kernel_launch(void* const* d_in, const int* in_sizes, int n_in,
                              void* d_out, int out_size, void* d_ws, size_t ws_size,
                              hipStream_t stream) {
    const int*   ids  = (const int*)d_in[0];
    const float* W    = (const float*)d_in[1];
    const float* bias = (const float*)d_in[2];
    float*       out  = (float*)d_out;

    const size_t need = (size_t)VOCAB * HIDDEN * sizeof(__half);
    if (ws_size >= need) {
        __half* WT = (__half*)d_ws;
        wt_transpose_f16<<<(VOCAB + TP_V - 1) / TP_V, 256, 0, stream>>>(W, WT);
        bag_gather_f16<<<BATCH, 512, 0, stream>>>(ids, WT, bias, out);
    } else {
        bag_direct_kernel<<<BATCH, HIDDEN, 0, stream>>>(ids, W, bias, out);
    }
}

// Round 7
// 107.692 us; speedup vs baseline: 1.0216x; 1.0111x over previous
//
#include <hip/hip_runtime.h>
#include <hip/hip_fp16.h>

#define VOCAB 100000
#define HIDDEN 128
#define BATCH 1024
#define LEN 200
#define TP_V 256   // vocab-tile of the transpose kernel

typedef float f32x4 __attribute__((ext_vector_type(4)));

// ---------------------------------------------------------------------------
// Kernel 1: transpose + downconvert  W f32 [HIDDEN][VOCAB] -> WT fp16 [VOCAB][HIDDEN]
// Block 512 threads, tile = 256 v x 128 h (full hidden dim).
// Global reads: per h-row, a 1 KB contiguous span (64 lanes x 16 B) -- 4x the
// DRAM page amortization of the previous 256 B spans (theory: read was
// page-thrash-bound at ~1.3 TB/s).
// LDS: fp16 tile[256][128] with XOR swizzle  h' = h ^ ((v&31)<<1):
//   - scatter-writes (fixed h, lanes span v): banks = (h>>1)^(v&31) -> all 32
//     banks across 32 lanes, 2-way over 64 lanes = free.
//   - pack-reads (b16): <=4-way, minor.
// Stores: thread packs 8 fp16 -> 16 B; wave = 4 rows x 256 B = 1 KB contiguous.
// ---------------------------------------------------------------------------
__global__ __launch_bounds__(512) void wt_transpose_f16(
    const float* __restrict__ W, __half* __restrict__ WT) {
    __shared__ __half tile[TP_V][HIDDEN];
    const int v0 = blockIdx.x * TP_V;
    const int t  = threadIdx.x;

    // Read phase: vq4 = float4 slot along v (64 x 4 = 256 v), hr = h sub-row.
    const int vq4 = t & 63;
    const int hr  = t >> 6;    // 0..7
#pragma unroll
    for (int p = 0; p < 16; ++p) {
        const int h  = p * 8 + hr;
        const int gv = v0 + vq4 * 4;
        f32x4 f;
        if (gv + 3 < VOCAB) {
            f = __builtin_nontemporal_load(
                reinterpret_cast<const f32x4*>(&W[(size_t)h * VOCAB + gv]));
        } else {
            f[0] = (gv + 0 < VOCAB) ? W[(size_t)h * VOCAB + gv + 0] : 0.f;
            f[1] = (gv + 1 < VOCAB) ? W[(size_t)h * VOCAB + gv + 1] : 0.f;
            f[2] = (gv + 2 < VOCAB) ? W[(size_t)h * VOCAB + gv + 2] : 0.f;
            f[3] = (gv + 3 < VOCAB) ? W[(size_t)h * VOCAB + gv + 3] : 0.f;
        }
#pragma unroll
        for (int k = 0; k < 4; ++k) {
            const int v = vq4 * 4 + k;
            tile[v][h ^ ((v & 31) << 1)] = __float2half_rn(f[k]);
        }
    }
    __syncthreads();

    // Store phase: c = 16B chunk in the 256 B output row, vr+32q = v row.
    const int c  = t & 15;
    const int vr = t >> 4;     // 0..31
#pragma unroll
    for (int q = 0; q < 8; ++q) {
        const int v  = vr + q * 32;
        const int gv = v0 + v;
        if (gv < VOCAB) {
            __half hb[8];
            const int sw = (v & 31) << 1;
#pragma unroll
            for (int j = 0; j < 8; ++j) hb[j] = tile[v][(c * 8 + j) ^ sw];
            *reinterpret_cast<float4*>(&WT[(size_t)gv * HIDDEN + c * 8]) =
                *reinterpret_cast<const float4*>(hb);
        }
    }
}

// ---------------------------------------------------------------------------
// Kernel 2: gather-sum from fp16 WT.  One block per batch row, 512 threads
// (8 waves; 1024 blocks -> 4 blocks/CU = full 32 waves/CU occupancy).
// t&15 = 16B-slot in the 256 B row (g), t>>4 = L-chunk (32 chunks).
// Fixed-trip predicated unroll-7 -> 7 independent gathers in flight/thread.
// Reduce: 2 shfl_xor folds (chunk bits in lane bits 4,5) -> part[8][128] ->
// single barrier -> 8-way sum + fused bias.
// ---------------------------------------------------------------------------
__global__ __launch_bounds__(512) void bag_gather_f16(
    const int* __restrict__ ids, const __half* __restrict__ WT,
    const float* __restrict__ bias, float* __restrict__ out) {
    __shared__ int   sid[LEN];
    __shared__ float part[8][HIDDEN];   // 4 KB

    const int b = blockIdx.x;
    const int t = threadIdx.x;

    for (int l = t; l < LEN; l += 512) sid[l] = ids[b * LEN + l];
    __syncthreads();

    const int g     = t & 15;
    const int chunk = t >> 4;

    float acc[8];
#pragma unroll
    for (int k = 0; k < 8; ++k) acc[k] = 0.f;

#pragma unroll
    for (int i = 0; i < 7; ++i) {
        const int  l  = chunk + i * 32;
        const bool ok = (l < LEN);
        const int  id = ok ? sid[l] : 0;
        const float4 q = *reinterpret_cast<const float4*>(
            WT + (size_t)id * HIDDEN + g * 8);
        if (ok) {
            const __half2* h2 = reinterpret_cast<const __half2*>(&q);
#pragma unroll
            for (int k = 0; k < 4; ++k) {
                const float2 f = __half22float2(h2[k]);
                acc[2 * k + 0] += f.x;
                acc[2 * k + 1] += f.y;
            }
        }
    }

#pragma unroll
    for (int k = 0; k < 8; ++k) {
        acc[k] += __shfl_xor(acc[k], 16);
        acc[k] += __shfl_xor(acc[k], 32);
    }
    const int wave = t >> 6;
    if ((t & 63) < 16) {
#pragma unroll
        for (int k = 0; k < 8; ++k) part[wave][g * 8 + k] = acc[k];
    }
    __syncthreads();

    if (t < HIDDEN) {
        float s = 0.f;
#pragma unroll
        for (int w = 0; w < 8; ++w) s += part[w][t];
        out[(size_t)b * HIDDEN + t] = s + bias[t];
    }
}

// ---------------------------------------------------------------------------
// Fallback (ws too small): direct strided gather from original W layout.
// ---------------------------------------------------------------------------
__global__ __launch_bounds__(HIDDEN) void bag_direct_kernel(
    const int* __restrict__ ids, const float* __restrict__ W,
    const float* __restrict__ bias, float* __restrict__ out) {
    __shared__ int sid[LEN];
    const int b = blockIdx.x;
    const int h = threadIdx.x;
    for (int l = h; l < LEN; l += HIDDEN) sid[l] = ids[b * LEN + l];
    __syncthreads();
    float acc = 0.f;
    for (int l = 0; l < LEN; ++l)
        acc += W[(size_t)h * VOCAB + sid[l]];
    out[(size_t)b * HIDDEN + h] = acc + bias[h];
}

extern "C" void kernel_launch(void* const* d_in, const int* in_sizes, int n_in,
                              void* d_out, int out_size, void* d_ws, size_t ws_size,
                              hipStream_t stream) {
    const int*   ids  = (const int*)d_in[0];
    const float* W    = (const float*)d_in[1];
    const float* bias = (const float*)d_in[2];
    float*       out  = (float*)d_out;

    const size_t need = (size_t)VOCAB * HIDDEN * sizeof(__half);
    if (ws_size >= need) {
        __half* WT = (__half*)d_ws;
        wt_transpose_f16<<<(VOCAB + TP_V - 1) / TP_V, 512, 0, stream>>>(W, WT);
        bag_gather_f16<<<BATCH, 512, 0, stream>>>(ids, WT, bias, out);
    } else {
        bag_direct_kernel<<<BATCH, HIDDEN, 0, stream>>>(ids, W, bias, out);
    }
}